// Round 9
// baseline (10148.824 us; speedup 1.0000x reference)
//
#include <hip/hip_runtime.h>
#include <math.h>

#define NOT_FIREDf 9999.0f
typedef float f32x2 __attribute__((ext_vector_type(2)));

// packed f32x2 add (bit-exact element-wise IEEE add, 1 inst for 2 adds)
#define PKADD(ACC, W) asm("v_pk_add_f32 %0, %0, %1" : "+v"(ACC) : "v"(W))
// compiler-only memory fence (orders LDS ops in program order; HW is in-order per wave)
#define CFENCE() asm volatile("" ::: "memory")

// Zero-padded conv2 weights in d_ws:
// w2p[((ci*5 + dy)*19 + rx)*64 + co] = (rx-7 in [0,5)) ? w2[(co*12+ci)*25 + dy*5 + (rx-7)] : 0
__global__ void w2_pad_kernel(const float* __restrict__ w2, float* __restrict__ w2p) {
    int idx = blockIdx.x * 256 + threadIdx.x;
    if (idx >= 72960) return;
    int co = idx & 63;
    int r = idx >> 6;            // ci*95 + dy*19 + rx
    int rx = r % 19;
    int q = r / 19;
    int dy = q % 5;
    int ci = q / 5;
    int dx = rx - 7;
    w2p[idx] = ((unsigned)dx < 5u) ? w2[(co * 12 + ci) * 25 + dy * 5 + dx] : 0.0f;
}

template <int USE_T>
__global__ void __launch_bounds__(256, 1)
snn_wave_kernel(const float* __restrict__ img,
                const float* __restrict__ w1g,
                const float* __restrict__ b1g,
                const float* __restrict__ b2g,
                const float* __restrict__ w2raw,
                const float* __restrict__ w2p,
                const float* __restrict__ fcw,
                const float* __restrict__ b3g,
                float* __restrict__ out,
                const int B) {
    const int tid  = threadIdx.x;
    const int lane = tid & 63;
    const int wv   = tid >> 6;               // 4 waves = 4 independent images
    const int bimg = blockIdx.x * 4 + wv;

    __shared__ __align__(16) float w1s[300]; // transposed [k=ky*5+kx][c], block-shared
    __shared__ __align__(8)  float b1s[12];
    __shared__ float th_lds[80];
    __shared__ unsigned char  stin[4][784];
    __shared__ unsigned short evlist[4][784];   // t-sorted input events (py<<8|px)
    __shared__ unsigned short off[4][81];
    __shared__ int            hist[4][80];
    __shared__ unsigned short ev1[4][1728];     // this-step pooled-l1 events (c<<8|py<<4|px)
    __shared__ int            cnt1[4];
    __shared__ unsigned int   pm1[4][54];
    __shared__ unsigned int   pm2[4][32];
    __shared__ unsigned int   e2list[4][1024];  // (t<<16)|nhwc_flat
    __shared__ int            e2cnt[4];

    // ---- block-shared init ----
    for (int i = tid; i < 300; i += 256) {
        int k = i / 12, c = i - k * 12;
        w1s[i] = w1g[c * 25 + k];
    }
    if (tid < 12) b1s[tid] = b1g[tid];
    if (tid < 80) {
        float xa = (0.0f - (float)tid) / 20.0f;
        th_lds[tid] = (float)exp((double)xa);           // correctly-rounded f32 exp
    }

    // ---- per-wave init (no cross-wave deps) ----
    const bool act = (bimg < B);
    if (act) {
        for (int i = lane; i < 80; i += 64) hist[wv][i] = 0;
        if (lane < 54) pm1[wv][lane] = 0u;
        if (lane < 32) pm2[wv][lane] = 0u;
        if (lane == 0) { cnt1[wv] = 0; e2cnt[wv] = 0; }
        CFENCE();
        for (int i = lane; i < 784; i += 64) {
            float p = img[bimg * 784 + i];
            p = fmaxf(p, 1e-5f);
            float lg = (float)log((double)p);           // correctly-rounded f32 log
            float s = ceilf(fmaxf(-17.452274f * lg, 0.0f));
            int si = (int)fminf(s, 255.0f);
            stin[wv][i] = (unsigned char)si;
            if (si < 80) atomicAdd(&hist[wv][si], 1);
        }
        CFENCE();
        if (lane == 0) {
            int acc = 0;
            for (int t = 0; t < 80; ++t) { off[wv][t] = (unsigned short)acc; acc += hist[wv][t]; }
            off[wv][80] = (unsigned short)acc;
        }
        CFENCE();
        {   // evlist fill: lane owns bins `lane` and `64+lane` (lane<16); pixel-order per bin
            int k0 = off[wv][lane];
            int k1 = (lane < 16) ? off[wv][64 + lane] : 0;
            int py = 0, px = 0;
            for (int i = 0; i < 784; ++i) {
                const int tt = stin[wv][i];             // broadcast read
                const unsigned pk = (unsigned)((py << 8) | px);
                if (tt == lane) evlist[wv][k0++] = (unsigned short)pk;
                if ((lane < 16) & (tt == 64 + lane)) evlist[wv][k1++] = (unsigned short)pk;
                if (++px == 28) { px = 0; ++py; }
            }
        }
        CFENCE();
    }
    __syncthreads();     // the ONLY block barrier (w1s/b1s/th ready)
    if (!act) return;

    // ---- register state ----
    // INTERLEAVED ownership: lane owns pixels (y0+8*gy, x0+8*gx), gy,gx in 0..2.
    // A 5x5 event footprint (span 5 < stride 8) hits <=2 gy and <=2 gx groups wave-wide.
    const int y0 = lane >> 3;
    const int x0 = lane & 7;
    f32x2 v1r[9][6];                          // [gy*3+gx][ch-pair]
#pragma unroll
    for (int g = 0; g < 9; ++g)
#pragma unroll
        for (int j = 0; j < 6; ++j) v1r[g][j] = (f32x2){0.0f, 0.0f};
    f32x2 acc2[32];                           // v2: pos (OY, ox) -> acc2[OY*4+(ox>>1)], co=lane
#pragma unroll
    for (int j = 0; j < 32; ++j) acc2[j] = (f32x2){0.0f, 0.0f};
    const float b2v = b2g[lane];
    const f32x2 b2p = (f32x2){b2v, b2v};

    // ---- time loop: NO barriers ----
    for (int t = 0; t < 80; ++t) {
        const float th = th_lds[t];

        // phase 1: input events -> v1 regs
        {
            const int e0 = off[wv][t], e1 = off[wv][t + 1];
            for (int e = e0; e < e1; ++e) {
                const unsigned pk = evlist[wv][e];      // broadcast
                const int ry = (int)(pk >> 8) - y0;
                const int rx = (int)(pk & 255u) - x0;
#pragma unroll
                for (int gy = 0; gy < 3; ++gy) {
                    const int dy = ry - 8 * gy;
                    if ((unsigned)dy < 5u) {
#pragma unroll
                        for (int gx = 0; gx < 3; ++gx) {
                            const int dx = rx - 8 * gx;
                            if ((unsigned)dx < 5u) {
                                const f32x2* wp = (const f32x2*)&w1s[(dy * 5 + dx) * 12];
                                f32x2 a0 = wp[0], a1 = wp[1], a2 = wp[2];
                                f32x2 a3 = wp[3], a4 = wp[4], a5 = wp[5];
                                PKADD(v1r[gy * 3 + gx][0], a0);
                                PKADD(v1r[gy * 3 + gx][1], a1);
                                PKADD(v1r[gy * 3 + gx][2], a2);
                                PKADD(v1r[gy * 3 + gx][3], a3);
                                PKADD(v1r[gy * 3 + gx][4], a4);
                                PKADD(v1r[gy * 3 + gx][5], a5);
                            }
                        }
                    }
                }
            }
        }
        // layer1 check: stepwise bias + per-group max screen + exact pass on crossing
        {
            const f32x2* bp = (const f32x2*)b1s;
            const f32x2 c0 = bp[0], c1 = bp[1], c2 = bp[2];
            const f32x2 c3 = bp[3], c4 = bp[4], c5 = bp[5];
#pragma unroll
            for (int g = 0; g < 9; ++g) {
                PKADD(v1r[g][0], c0); PKADD(v1r[g][1], c1); PKADD(v1r[g][2], c2);
                PKADD(v1r[g][3], c3); PKADD(v1r[g][4], c4); PKADD(v1r[g][5], c5);
                float m = fmaxf(fmaxf(fmaxf(v1r[g][0].x, v1r[g][0].y),
                                      fmaxf(v1r[g][1].x, v1r[g][1].y)),
                                fmaxf(fmaxf(v1r[g][2].x, v1r[g][2].y),
                                      fmaxf(v1r[g][3].x, v1r[g][3].y)));
                m = fmaxf(m, fmaxf(fmaxf(v1r[g][4].x, v1r[g][4].y),
                                   fmaxf(v1r[g][5].x, v1r[g][5].y)));
                if (m >= th) {
                    const int Y = y0 + 8 * (g / 3), X = x0 + 8 * (g % 3);  // compile-time g/3,g%3
                    const int pyp = Y >> 1, pxp = X >> 1;
#pragma unroll
                    for (int j = 0; j < 6; ++j) {
                        if (v1r[g][j].x >= th) {
                            v1r[g][j].x = -__builtin_inff();
                            const int p = (j * 2) * 144 + pyp * 12 + pxp;
                            const unsigned bit = 1u << (p & 31);
                            const unsigned old = atomicOr(&pm1[wv][p >> 5], bit);
                            if (!(old & bit)) {
                                const int pos = atomicAdd(&cnt1[wv], 1);
                                ev1[wv][pos] = (unsigned short)(((j * 2) << 8) | (pyp << 4) | pxp);
                            }
                        }
                        if (v1r[g][j].y >= th) {
                            v1r[g][j].y = -__builtin_inff();
                            const int p = (j * 2 + 1) * 144 + pyp * 12 + pxp;
                            const unsigned bit = 1u << (p & 31);
                            const unsigned old = atomicOr(&pm1[wv][p >> 5], bit);
                            if (!(old & bit)) {
                                const int pos = atomicAdd(&cnt1[wv], 1);
                                ev1[wv][pos] = (unsigned short)(((j * 2 + 1) << 8) | (pyp << 4) | pxp);
                            }
                        }
                    }
                }
            }
        }
        CFENCE();

        // phase 2: pooled-l1 events -> v2 (scalar decode, all 8 rows in this wave)
        {
            const int ne1 = cnt1[wv];
            for (int e = 0; e < ne1; ++e) {
                const int pks = __builtin_amdgcn_readfirstlane((int)ev1[wv][e]);
                const int ci = pks >> 8;
                const int py = (pks >> 4) & 15;
                const int px = pks & 15;
                if (USE_T) {
                    const float* qb = w2p + (px + 7) * 64 + lane;
#pragma unroll
                    for (int OY = 0; OY < 8; ++OY) {
                        const int dy = py - OY;                    // scalar
                        if ((unsigned)dy < 5u) {                   // scalar branch
                            const float* q = qb + (ci * 5 + dy) * 1216;
#pragma unroll
                            for (int i = 0; i < 4; ++i) {
                                f32x2 w;
                                w.x = q[-((2 * i) * 64)];
                                w.y = q[-((2 * i + 1) * 64)];
                                PKADD(acc2[OY * 4 + i], w);
                            }
                        }
                    }
                } else {
                    const float* cb = w2raw + (lane * 12 + ci) * 25;
#pragma unroll
                    for (int OY = 0; OY < 8; ++OY) {
                        const int dy = py - OY;
                        if ((unsigned)dy < 5u) {
                            const float* r = cb + dy * 5;
#pragma unroll
                            for (int i = 0; i < 4; ++i) {
                                const int dxa = px - 2 * i;
                                const int dxb = dxa - 1;
                                const int dxac = dxa < 0 ? 0 : (dxa > 4 ? 4 : dxa);
                                const int dxbc = dxb < 0 ? 0 : (dxb > 4 ? 4 : dxb);
                                acc2[OY * 4 + i].x = fmaf(r[dxac],
                                    ((unsigned)dxa < 5u) ? 1.0f : 0.0f, acc2[OY * 4 + i].x);
                                acc2[OY * 4 + i].y = fmaf(r[dxbc],
                                    ((unsigned)dxb < 5u) ? 1.0f : 0.0f, acc2[OY * 4 + i].y);
                            }
                        }
                    }
                }
            }
            CFENCE();
            if (lane == 0) cnt1[wv] = 0;
            CFENCE();
        }

        // layer2 check: stepwise bias + per-row max screen + exact pass
        {
#pragma unroll
            for (int OY = 0; OY < 8; ++OY) {
                PKADD(acc2[OY * 4 + 0], b2p); PKADD(acc2[OY * 4 + 1], b2p);
                PKADD(acc2[OY * 4 + 2], b2p); PKADD(acc2[OY * 4 + 3], b2p);
                float m = fmaxf(fmaxf(fmaxf(acc2[OY * 4 + 0].x, acc2[OY * 4 + 0].y),
                                      fmaxf(acc2[OY * 4 + 1].x, acc2[OY * 4 + 1].y)),
                                fmaxf(fmaxf(acc2[OY * 4 + 2].x, acc2[OY * 4 + 2].y),
                                      fmaxf(acc2[OY * 4 + 3].x, acc2[OY * 4 + 3].y)));
                if (m >= th) {
#pragma unroll
                    for (int i = 0; i < 4; ++i) {
                        if (acc2[OY * 4 + i].x >= th) {
                            acc2[OY * 4 + i].x = -__builtin_inff();
                            const int p2 = ((OY >> 1) * 4 + ((2 * i) >> 1)) * 64 + lane;
                            const unsigned bit = 1u << (p2 & 31);
                            const unsigned old = atomicOr(&pm2[wv][p2 >> 5], bit);
                            if (!(old & bit)) {
                                const int pos = atomicAdd(&e2cnt[wv], 1);
                                e2list[wv][pos] = ((unsigned)t << 16) | (unsigned)p2;
                            }
                        }
                        if (acc2[OY * 4 + i].y >= th) {
                            acc2[OY * 4 + i].y = -__builtin_inff();
                            const int p2 = ((OY >> 1) * 4 + ((2 * i + 1) >> 1)) * 64 + lane;
                            const unsigned bit = 1u << (p2 & 31);
                            const unsigned old = atomicOr(&pm2[wv][p2 >> 5], bit);
                            if (!(old & bit)) {
                                const int pos = atomicAdd(&e2cnt[wv], 1);
                                e2list[wv][pos] = ((unsigned)t << 16) | (unsigned)p2;
                            }
                        }
                    }
                }
            }
        }
        CFENCE();
    }

    // ---- output layer: replay t-sorted layer2 event log (no feedback) ----
    if (lane < 10) {
        const int n2 = e2cnt[wv];
        const float b3v = b3g[lane];
        float v = 0.0f;
        float ot = NOT_FIREDf;
        int ptr = 0;
        for (int t = 0; t < 80; ++t) {
            float acc = 0.0f;
            while (ptr < n2 && (int)(e2list[wv][ptr] >> 16) == t) {
                acc += fcw[(e2list[wv][ptr] & 0xFFFFu) * 10 + lane];
                ++ptr;
            }
            v += acc + b3v;
            if (ot == NOT_FIREDf && v >= th_lds[t]) ot = (float)t;
        }
        out[bimg * 10 + lane] = ot;
    }
}

extern "C" void kernel_launch(void* const* d_in, const int* in_sizes, int n_in,
                              void* d_out, int out_size, void* d_ws, size_t ws_size,
                              hipStream_t stream) {
    const float* img = (const float*)d_in[0];
    const float* w1  = (const float*)d_in[1];
    const float* b1  = (const float*)d_in[2];
    const float* w2  = (const float*)d_in[3];
    const float* b2  = (const float*)d_in[4];
    const float* fcw = (const float*)d_in[5];
    const float* b3  = (const float*)d_in[6];
    float* out = (float*)d_out;

    const int B = in_sizes[0] / (28 * 28);
    const int nblk = (B + 3) / 4;

    float* w2p = (float*)d_ws;
    const int use_t = (ws_size >= 72960u * sizeof(float)) ? 1 : 0;
    if (use_t) {
        hipLaunchKernelGGL(w2_pad_kernel, dim3(285), dim3(256), 0, stream, w2, w2p);
        hipLaunchKernelGGL(snn_wave_kernel<1>, dim3(nblk), dim3(256), 0, stream,
                           img, w1, b1, b2, w2, w2p, fcw, b3, out, B);
    } else {
        hipLaunchKernelGGL(snn_wave_kernel<0>, dim3(nblk), dim3(256), 0, stream,
                           img, w1, b1, b2, w2, w2p, fcw, b3, out, B);
    }
}

// Round 10
// 3941.603 us; speedup vs baseline: 2.5748x; 2.5748x over previous
//
#include <hip/hip_runtime.h>
#include <math.h>

#define NOT_FIREDf 9999.0f
typedef float f32x2 __attribute__((ext_vector_type(2)));

// packed f32x2 add (bit-exact element-wise IEEE add, 1 inst for 2 adds)
#define PKADD(ACC, W) asm("v_pk_add_f32 %0, %0, %1" : "+v"(ACC) : "v"(W))

// Zero-padded conv2 weights in d_ws:
// w2p[((ci*5 + dy)*19 + rx)*64 + co] = (rx-7 in [0,5)) ? w2[(co*12+ci)*25 + dy*5 + (rx-7)] : 0
// plus a 19*64 zero row at w2p + 72960.
__global__ void w2_pad_kernel(const float* __restrict__ w2, float* __restrict__ w2p) {
    int idx = blockIdx.x * 256 + threadIdx.x;
    if (idx >= 74176) return;
    if (idx >= 72960) { w2p[idx] = 0.0f; return; }
    int co = idx & 63;
    int r = idx >> 6;            // ci*95 + dy*19 + rx
    int rx = r % 19;
    int q = r / 19;
    int dy = q % 5;
    int ci = q / 5;
    int dx = rx - 7;
    w2p[idx] = ((unsigned)dx < 5u) ? w2[(co * 12 + ci) * 25 + dy * 5 + dx] : 0.0f;
}

// v1 gather: 6 pk-adds of one w1 row (12 ch) into reg pairs
#define GATHER_V1(S, Y, X) do {                                              \
    const int dy_ = py - (Y), dx_ = px - (X);                                \
    if (((unsigned)dy_ < 5u) & ((unsigned)dx_ < 5u)) {                       \
        const f32x2* wp_ = (const f32x2*)&w1s[(dy_ * 5 + dx_) * 12];         \
        PKADD(v1r[S][0], wp_[0]); PKADD(v1r[S][1], wp_[1]);                  \
        PKADD(v1r[S][2], wp_[2]); PKADD(v1r[S][3], wp_[3]);                  \
        PKADD(v1r[S][4], wp_[4]); PKADD(v1r[S][5], wp_[5]);                  \
    } } while (0)

#define P1EVENT(PK) do {                                                     \
    const int py = (int)((PK) >> 8);                                         \
    const int px = (int)((PK) & 255u);                                       \
    GATHER_V1(0, y0, x0);                                                    \
    GATHER_V1(1, y1, x1);                                                    \
    if (has2) GATHER_V1(2, y2, x2);                                          \
  } while (0)

// stepwise bias pk-add + max-screen; exact per-channel pass only on crossing
#define CHECK_V1G(S, Y, X) do {                                              \
    PKADD(v1r[S][0], b1p[0]); PKADD(v1r[S][1], b1p[1]);                      \
    PKADD(v1r[S][2], b1p[2]); PKADD(v1r[S][3], b1p[3]);                      \
    PKADD(v1r[S][4], b1p[4]); PKADD(v1r[S][5], b1p[5]);                      \
    float m_ = fmaxf(fmaxf(fmaxf(v1r[S][0].x, v1r[S][0].y),                  \
                           fmaxf(v1r[S][1].x, v1r[S][1].y)),                 \
                     fmaxf(fmaxf(v1r[S][2].x, v1r[S][2].y),                  \
                           fmaxf(v1r[S][3].x, v1r[S][3].y)));                \
    m_ = fmaxf(m_, fmaxf(fmaxf(v1r[S][4].x, v1r[S][4].y),                    \
                         fmaxf(v1r[S][5].x, v1r[S][5].y)));                  \
    if (m_ >= th) {                                                          \
        _Pragma("unroll")                                                    \
        for (int jj = 0; jj < 6; ++jj) {                                     \
            _Pragma("unroll")                                                \
            for (int el = 0; el < 2; ++el) {                                 \
                const float v_ = el ? v1r[S][jj].y : v1r[S][jj].x;           \
                if (v_ >= th) {                                              \
                    if (el) v1r[S][jj].y = -__builtin_inff();                \
                    else    v1r[S][jj].x = -__builtin_inff();                \
                    const int c_ = jj * 2 + el;                              \
                    const int pyp_ = (Y) >> 1, pxp_ = (X) >> 1;              \
                    const int p_ = c_ * 144 + pyp_ * 12 + pxp_;              \
                    const unsigned bit_ = 1u << (p_ & 31);                   \
                    const unsigned old_ = atomicOr(&pm1[p_ >> 5], bit_);     \
                    if (!(old_ & bit_)) {                                    \
                        const int pos_ = atomicAdd(&cnt1[t], 1);             \
                        ev1b[t & 1][pos_] =                                  \
                            (unsigned short)((c_ << 8) | (pyp_ << 4) | pxp_);\
                    }                                                        \
                }                                                            \
            }                                                                \
        }                                                                    \
    } } while (0)

// one phase-2 event: 16 zero-padded loads -> 8 pk-adds (register-lean)
#define P2_ONE(PA) do {                                                      \
    const int dA_ = (((PA) >> 4) & 15) - oyb_s;                              \
    if ((unsigned)dA_ < 6u) {                                                \
        const int ci_ = (PA) >> 8;                                           \
        const int px_ = (PA) & 15;                                           \
        const float* r0_ = (dA_ <= 4) ? (w2p + (ci_ * 5 + dA_) * 1216) : zrow; \
        const float* r1_ = (dA_ >= 1) ? (w2p + (ci_ * 5 + dA_ - 1) * 1216) : zrow; \
        const float* q0_ = r0_ + (px_ + 7) * 64 + lane;                      \
        const float* q1_ = r1_ + (px_ + 7) * 64 + lane;                      \
        f32x2 la_[8];                                                        \
        _Pragma("unroll")                                                    \
        for (int j = 0; j < 8; ++j) { la_[j].x = q0_[-(j * 64)]; la_[j].y = q1_[-(j * 64)]; } \
        _Pragma("unroll")                                                    \
        for (int j = 0; j < 8; ++j) PKADD(v2r2[j], la_[j]);                  \
    } } while (0)

template <int USE_T>
__global__ void __launch_bounds__(256, 5)
snn_sim_kernel(const float* __restrict__ img,
               const float* __restrict__ w1g,
               const float* __restrict__ b1g,
               const float* __restrict__ b2g,
               const float* __restrict__ w2raw,
               const float* __restrict__ w2p,
               const float* __restrict__ fcw,
               const float* __restrict__ b3g,
               float* __restrict__ out) {
    const int bimg = blockIdx.x;
    const int tid  = threadIdx.x;
    const int lane = tid & 63;
    const int wv   = tid >> 6;   // 4 waves
    const int oyb_s = __builtin_amdgcn_readfirstlane(wv) * 2;   // wave-uniform SGPR

    __shared__ __align__(16) float w1s[300];   // transposed: [k=ky*5+kx][c]
    __shared__ float b1s[12];
    __shared__ float th_lds[80];
    __shared__ unsigned char  stin[784];
    __shared__ unsigned short evlist[784];     // t-sorted schedule, packed (py<<8|px)
    __shared__ unsigned short off[81];
    __shared__ unsigned int   hist[80];
    __shared__ __align__(8) unsigned short ev1b[2][1728];  // pooled-l1 events, dbuf
    __shared__ int            cnt1[80];        // per-step counters, never reset
    __shared__ unsigned int   pm1[54];
    __shared__ unsigned int   pm2[32];
    __shared__ unsigned int   e2list[1024];    // persistent: (t<<16) | nhwc_flat_idx
    __shared__ int            e2_cnt;

    // ---- init ----
    for (int i = tid; i < 300; i += 256) {
        int k = i / 12, c = i - k * 12;
        w1s[i] = w1g[c * 25 + k];
    }
    if (tid < 12) b1s[tid] = b1g[tid];
    if (tid < 80) {
        float xa = (0.0f - (float)tid) / 20.0f;
        th_lds[tid] = (float)exp((double)xa);            // correctly-rounded f32 exp
        hist[tid] = 0u;
        cnt1[tid] = 0;
    }
    if (tid < 54) pm1[tid] = 0u;
    if (tid < 32) pm2[tid] = 0u;
    if (tid == 0) e2_cnt = 0;
    for (int i = tid; i < 784; i += 256) {
        float p = img[bimg * 784 + i];
        p = fmaxf(p, 1e-5f);
        float lg = (float)log((double)p);                // correctly-rounded f32 log
        float s = ceilf(fmaxf(-17.452274f * lg, 0.0f));
        stin[i] = (unsigned char)(int)fminf(s, 255.0f);
    }
    __syncthreads();
    for (int i = tid; i < 784; i += 256) {
        int t = stin[i];
        if (t < 80) atomicAdd(&hist[t], 1u);
    }
    __syncthreads();
    if (tid == 0) {
        unsigned int acc = 0;
        for (int t = 0; t < 80; ++t) { off[t] = (unsigned short)acc; acc += hist[t]; }
        off[80] = (unsigned short)acc;
    }
    __syncthreads();
    if (tid < 80) {                            // deterministic pixel-order fill per t-bin
        int k = off[tid];
        for (int i = 0; i < 784; ++i)
            if ((int)stin[i] == tid) {
                int py = i / 28;
                evlist[k++] = (unsigned short)((py << 8) | (i - py * 28));
            }
    }
    __syncthreads();

    // ---- register state ----
    f32x2 v1r[3][6];
#pragma unroll
    for (int s = 0; s < 3; ++s)
#pragma unroll
        for (int j = 0; j < 6; ++j) v1r[s][j] = (f32x2){0.0f, 0.0f};
    f32x2 v2r2[8];                             // .x = row oyb, .y = row oyb+1, col j, co=lane
#pragma unroll
    for (int j = 0; j < 8; ++j) v2r2[j] = (f32x2){0.0f, 0.0f};

    f32x2 b1p[6];
#pragma unroll
    for (int j = 0; j < 6; ++j) b1p[j] = (f32x2){b1s[j * 2], b1s[j * 2 + 1]};
    const float b2v = b2g[lane];
    const f32x2 b2p = (f32x2){b2v, b2v};
    const float* zrow = w2p + 72960;

    const int y0 = tid / 24,  x0 = tid - y0 * 24;
    const int p1i = tid + 256;
    const int y1 = p1i / 24,  x1 = p1i - y1 * 24;
    const int has2 = (tid < 64);
    const int p2i = tid + 512;
    const int y2 = p2i / 24,  x2 = p2i - y2 * 24;

    // ---- time loop: ONE barrier per step ----
    for (int t = 0; t < 80; ++t) {
        const float th = th_lds[t];

        // phase 1: gather input events into v1 reg pairs (unroll-4 prefetch)
        {
            const int e0 = off[t], e1t = off[t + 1];
            int e = e0;
            for (; e + 4 <= e1t; e += 4) {
                const unsigned a0 = evlist[e];
                const unsigned a1 = evlist[e + 1];
                const unsigned a2 = evlist[e + 2];
                const unsigned a3 = evlist[e + 3];
                P1EVENT(a0); P1EVENT(a1); P1EVENT(a2); P1EVENT(a3);
            }
            for (; e < e1t; ++e) { const unsigned a = evlist[e]; P1EVENT(a); }
        }
        CHECK_V1G(0, y0, x0);
        CHECK_V1G(1, y1, x1);
        if (has2) CHECK_V1G(2, y2, x2);
        __syncthreads();                       // B1: ev1b[t&1]/cnt1[t] complete

        // phase 2: pooled-l1 events -> v2 (4 events per ds_read_b64, sequential P2)
        {
            const int ne1 = cnt1[t];
            const unsigned short* evp = ev1b[t & 1];
            if (USE_T) {
                int e = 0;
                for (; e + 4 <= ne1; e += 4) {
                    const unsigned long long pk4 = *(const unsigned long long*)&evp[e];
                    const unsigned lo = (unsigned)__builtin_amdgcn_readfirstlane((int)(unsigned)pk4);
                    const unsigned hi = (unsigned)__builtin_amdgcn_readfirstlane((int)(unsigned)(pk4 >> 32));
                    const int p0 = (int)(lo & 0xFFFFu), p1 = (int)(lo >> 16);
                    const int p2 = (int)(hi & 0xFFFFu), p3 = (int)(hi >> 16);
                    P2_ONE(p0); P2_ONE(p1); P2_ONE(p2); P2_ONE(p3);
                }
                for (; e < ne1; ++e) {
                    const int p0 = __builtin_amdgcn_readfirstlane((int)evp[e]);
                    P2_ONE(p0);
                }
            } else {
                for (int e = 0; e < ne1; ++e) {
                    const int pk = __builtin_amdgcn_readfirstlane((int)evp[e]);
                    const int dy0 = ((pk >> 4) & 15) - oyb_s;
                    if ((unsigned)dy0 >= 6u) continue;
                    const int ci = pk >> 8;
                    const int px = pk & 15;
                    const int dy1 = dy0 - 1;
                    const unsigned colm = ((0x1Fu << px) >> 4) & 0xFFu;
                    const unsigned m0 = ((unsigned)dy0 < 5u) ? colm : 0u;
                    const unsigned m1 = ((unsigned)dy1 < 5u) ? colm : 0u;
                    const int dy0c = dy0 < 0 ? 0 : (dy0 > 4 ? 4 : dy0);
                    const int dy1c = dy1 < 0 ? 0 : (dy1 > 4 ? 4 : dy1);
                    const float* cb = w2raw + lane * 300 + ci * 25;
                    const float* r0 = cb + dy0c * 5;
                    const float* r1 = cb + dy1c * 5;
#pragma unroll
                    for (int j = 0; j < 8; ++j) {
                        const int dx = px - j;
                        const int dxc = dx < 0 ? 0 : (dx > 4 ? 4 : dx);
                        v2r2[j].x = fmaf(r0[dxc], ((m0 >> j) & 1u) ? 1.0f : 0.0f, v2r2[j].x);
                        v2r2[j].y = fmaf(r1[dxc], ((m1 >> j) & 1u) ? 1.0f : 0.0f, v2r2[j].y);
                    }
                }
            }
        }
        // layer2: stepwise bias pk-add + max-screen + rare exact pass
        {
            PKADD(v2r2[0], b2p); PKADD(v2r2[1], b2p);
            PKADD(v2r2[2], b2p); PKADD(v2r2[3], b2p);
            PKADD(v2r2[4], b2p); PKADD(v2r2[5], b2p);
            PKADD(v2r2[6], b2p); PKADD(v2r2[7], b2p);
            float m2 = fmaxf(fmaxf(fmaxf(v2r2[0].x, v2r2[0].y), fmaxf(v2r2[1].x, v2r2[1].y)),
                             fmaxf(fmaxf(v2r2[2].x, v2r2[2].y), fmaxf(v2r2[3].x, v2r2[3].y)));
            m2 = fmaxf(m2, fmaxf(fmaxf(fmaxf(v2r2[4].x, v2r2[4].y), fmaxf(v2r2[5].x, v2r2[5].y)),
                                 fmaxf(fmaxf(v2r2[6].x, v2r2[6].y), fmaxf(v2r2[7].x, v2r2[7].y))));
            if (m2 >= th) {
#pragma unroll
                for (int j = 0; j < 8; ++j) {
#pragma unroll
                    for (int el = 0; el < 2; ++el) {
                        const float v = el ? v2r2[j].y : v2r2[j].x;
                        if (v >= th) {
                            if (el) v2r2[j].y = -__builtin_inff();
                            else    v2r2[j].x = -__builtin_inff();
                            const int oy = oyb_s + el;
                            const int p2 = ((oy >> 1) * 4 + (j >> 1)) * 64 + lane;  // NHWC flat
                            const unsigned bit = 1u << (p2 & 31);
                            const unsigned old = atomicOr(&pm2[p2 >> 5], bit);
                            if (!(old & bit)) {
                                const int pos = atomicAdd(&e2_cnt, 1);
                                e2list[pos] = ((unsigned)t << 16) | (unsigned)p2;
                            }
                        }
                    }
                }
            }
        }
        // no second barrier: next step's phase 1 touches only ev1b[(t+1)&1]/cnt1[t+1]
    }
    __syncthreads();                           // e2list complete

    // ---- output layer: replay t-sorted layer2 event log (no feedback) ----
    if (tid < 10) {
        const int n2 = e2_cnt;
        const float b3v = b3g[tid];
        float v = 0.0f;
        float ot = NOT_FIREDf;
        int ptr = 0;
        for (int t = 0; t < 80; ++t) {
            float acc = 0.0f;
            while (ptr < n2 && (int)(e2list[ptr] >> 16) == t) {
                acc += fcw[(e2list[ptr] & 0xFFFFu) * 10 + tid];
                ++ptr;
            }
            v += acc + b3v;
            if (ot == NOT_FIREDf && v >= th_lds[t]) ot = (float)t;
        }
        out[bimg * 10 + tid] = ot;
    }
}

extern "C" void kernel_launch(void* const* d_in, const int* in_sizes, int n_in,
                              void* d_out, int out_size, void* d_ws, size_t ws_size,
                              hipStream_t stream) {
    const float* img = (const float*)d_in[0];
    const float* w1  = (const float*)d_in[1];
    const float* b1  = (const float*)d_in[2];
    const float* w2  = (const float*)d_in[3];
    const float* b2  = (const float*)d_in[4];
    const float* fcw = (const float*)d_in[5];
    const float* b3  = (const float*)d_in[6];
    float* out = (float*)d_out;

    const int B = in_sizes[0] / (28 * 28);

    float* w2p = (float*)d_ws;
    const int use_t = (ws_size >= 74176u * sizeof(float)) ? 1 : 0;
    if (use_t) {
        hipLaunchKernelGGL(w2_pad_kernel, dim3(290), dim3(256), 0, stream, w2, w2p);
        hipLaunchKernelGGL(snn_sim_kernel<1>, dim3(B), dim3(256), 0, stream,
                           img, w1, b1, b2, w2, w2p, fcw, b3, out);
    } else {
        hipLaunchKernelGGL(snn_sim_kernel<0>, dim3(B), dim3(256), 0, stream,
                           img, w1, b1, b2, w2, w2p, fcw, b3, out);
    }
}